// Round 1
// 144.395 us; speedup vs baseline: 1.0320x; 1.0320x over previous
//
#include <hip/hip_runtime.h>

// BlocksparseFixedSelfAttention: B=4, T=2048, EMB=512, KBLK=64.
// R7: kqv_gemm rewritten as 256x256-tile / BK=64 / 512-thread 8-phase pipeline
// (m201 template: T2 LDS swizzle + T3/T4 counted vmcnt + T5 setprio + XCD swz).
// prep/wc_gemm/heads unchanged from R6.
// ws (MB): KQV bf16 32 @0 | xb 8 @32 | wcat bf16 2048x512 @40 | wvtb @42 |
//          wub @43 | biascat @44

typedef unsigned short u16;
typedef __attribute__((ext_vector_type(8))) short short8;
typedef __attribute__((ext_vector_type(4))) float f32x4;

constexpr int TDIM  = 2048;
constexpr int EMB_D = 512;
constexpr int BB    = 4;
constexpr int NBLK  = 32;    // T / 64
constexpr int LDK   = 2048;  // KQV row stride (u16)

__device__ __forceinline__ u16 f2b(float f) {
    unsigned u = __float_as_uint(f);
    unsigned r = (u + 0x7FFFu + ((u >> 16) & 1u)) >> 16;
    return (u16)r;
}

// ---------------------------------------------------------------------------
// prep (one launch, all parts independent, memory-bound):
//  [0,4096)    cast x -> xb
//  [4096,4352) cast Wk -> wcat[0:512]
//  [4352,4608) cast Wq -> wcat[512:1024]
//  [4608,5120) cast Wu -> wub
//  [5120,5184) transpose-cast Wv -> wvtb[k][j]
//  [5184,5200) biascat[1024+o] = Wu[o&511][.] . bv  (4 lanes/output + shfl)
//  5200        biascat[0:1024] = [bk|bq]
// ---------------------------------------------------------------------------
__global__ __launch_bounds__(256) void prep_k(
    const float* __restrict__ x, const float* __restrict__ Wk, const float* __restrict__ Wq,
    const float* __restrict__ Wv, const float* __restrict__ Wu,
    const float* __restrict__ bk, const float* __restrict__ bq, const float* __restrict__ bv,
    u16* __restrict__ xb, u16* __restrict__ wcat, u16* __restrict__ wvtb,
    u16* __restrict__ wub, float* __restrict__ biascat)
{
    const int bid = blockIdx.x, tid = threadIdx.x;
    if (bid < 5120) {
        const float* src; u16* dst; int base;
        if (bid < 4096)      { src = x;  dst = xb;            base = bid * 1024; }
        else if (bid < 4352) { src = Wk; dst = wcat;          base = (bid - 4096) * 1024; }
        else if (bid < 4608) { src = Wq; dst = wcat + 262144; base = (bid - 4352) * 1024; }
        else                 { src = Wu; dst = wub;           base = (bid - 4608) * 1024; }
        const int idx = base + tid * 4;
        float4 v = *(const float4*)(src + idx);
        ushort4 o = { f2b(v.x), f2b(v.y), f2b(v.z), f2b(v.w) };
        *(ushort4*)(dst + idx) = o;
    } else if (bid < 5184) {
        // 64x64 transpose tile of Wv
        __shared__ float T[64][65];
        const int t = bid - 5120;
        const int j0 = (t >> 3) * 64, k0 = (t & 7) * 64;
        const int rr = tid >> 4, c4 = (tid & 15) * 4;
        #pragma unroll
        for (int it = 0; it < 4; ++it) {
            const int j = rr + it * 16;
            float4 v = *(const float4*)(Wv + (size_t)(j0 + j) * 512 + k0 + c4);
            T[c4+0][j] = v.x; T[c4+1][j] = v.y; T[c4+2][j] = v.z; T[c4+3][j] = v.w;
        }
        __syncthreads();
        #pragma unroll
        for (int it = 0; it < 4; ++it) {
            const int k = rr + it * 16;
            ushort4 o = { f2b(T[k][c4+0]), f2b(T[k][c4+1]), f2b(T[k][c4+2]), f2b(T[k][c4+3]) };
            *(ushort4*)(wvtb + (size_t)(k0 + k) * 512 + j0 + c4) = o;
        }
    } else if (bid < 5200) {
        // Wu.bv dot: output o = (bid-5184)*64 + tid/4, lane-part p = tid%4
        const int o = (bid - 5184) * 64 + (tid >> 2);
        const int p = tid & 3;
        const int n = o & 511, half = o >> 9;
        const float* wr = Wu + (size_t)n * 1024 + half * 512 + p * 128;
        const float* br = bv + p * 128;
        float s = 0.f;
        #pragma unroll
        for (int j = 0; j < 128; j += 4) {
            float4 a = *(const float4*)(wr + j);
            float4 b = *(const float4*)(br + j);
            s += a.x*b.x + a.y*b.y + a.z*b.z + a.w*b.w;
        }
        s += __shfl_xor(s, 1);
        s += __shfl_xor(s, 2);
        if (p == 0) biascat[1024 + o] = s;
    } else {
        const int idx = tid * 4;
        float4 v = (idx < 512) ? *(const float4*)(bk + idx)
                               : *(const float4*)(bq + idx - 512);
        *(float4*)(biascat + idx) = v;
    }
}

// ---------------------------------------------------------------------------
// wc_gemm: Wc[m][k] = sum_j wub[m&511][ (m>>9)*512 + j ] * wvtb[k][j]
// -> wcat rows 1024+m. bf16 MFMA, 128x128 tile, BK=32 (m97 structure).
// grid (8,4). M=1024, N=512, K=512.
// ---------------------------------------------------------------------------
__global__ __launch_bounds__(256) void wc_gemm_k(
    const u16* __restrict__ wub, const u16* __restrict__ wvtb, u16* __restrict__ wcat)
{
    __shared__ u16 As[128 * 32];
    __shared__ u16 Bs[128 * 32];
    const int bm = blockIdx.x * 128;
    const int bn = blockIdx.y * 128;
    const int tid  = threadIdx.x;
    const int wid  = tid >> 6;
    const int lane = tid & 63;
    const int l15  = lane & 15;
    const int quad = lane >> 4;
    const int wm = (wid & 1) * 64;
    const int wn = (wid >> 1) * 64;

    f32x4 acc[4][4] = {};

    const int srow  = tid >> 2;
    const int skoff = (tid & 3) * 8;
    const int m0 = bm + srow, m1 = bm + 64 + srow;
    const u16* Ag0 = wub + (size_t)(m0 & 511) * 1024 + (m0 >> 9) * 512 + skoff;
    const u16* Ag1 = wub + (size_t)(m1 & 511) * 1024 + (m1 >> 9) * 512 + skoff;
    const u16* Bg  = wvtb + (size_t)(bn + srow) * 512 + skoff;
    char* AsBase = (char*)As + wid * 1024;
    char* BsBase = (char*)Bs + wid * 1024;

    for (int k0 = 0; k0 < 512; k0 += 32) {
        __syncthreads();
        __builtin_amdgcn_global_load_lds(
            (const __attribute__((address_space(1))) void*)(Ag0 + k0),
            (__attribute__((address_space(3))) void*)AsBase, 16, 0, 0);
        __builtin_amdgcn_global_load_lds(
            (const __attribute__((address_space(1))) void*)(Ag1 + k0),
            (__attribute__((address_space(3))) void*)(AsBase + 4096), 16, 0, 0);
        __builtin_amdgcn_global_load_lds(
            (const __attribute__((address_space(1))) void*)(Bg + k0),
            (__attribute__((address_space(3))) void*)BsBase, 16, 0, 0);
        __builtin_amdgcn_global_load_lds(
            (const __attribute__((address_space(1))) void*)(Bg + (size_t)64 * 512 + k0),
            (__attribute__((address_space(3))) void*)(BsBase + 4096), 16, 0, 0);
        __syncthreads();

        short8 a[4], b[4];
        #pragma unroll
        for (int i = 0; i < 4; ++i)
            a[i] = *(const short8*)((const short*)As + (wm + 16 * i + l15) * 32 + quad * 8);
        #pragma unroll
        for (int j = 0; j < 4; ++j)
            b[j] = *(const short8*)((const short*)Bs + (wn + 16 * j + l15) * 32 + quad * 8);
        #pragma unroll
        for (int i = 0; i < 4; ++i)
            #pragma unroll
            for (int j = 0; j < 4; ++j)
                acc[i][j] = __builtin_amdgcn_mfma_f32_16x16x32_bf16(a[i], b[j], acc[i][j], 0, 0, 0);
    }

    #pragma unroll
    for (int i = 0; i < 4; ++i)
        #pragma unroll
        for (int j = 0; j < 4; ++j) {
            const int col = bn + wn + 16 * j + l15;
            #pragma unroll
            for (int r = 0; r < 4; ++r) {
                const int row = bm + wm + 16 * i + quad * 4 + r;
                wcat[(size_t)(1024 + row) * 512 + col] = f2b(acc[i][j][r]);
            }
        }
}

// ---------------------------------------------------------------------------
// KQV GEMM (R7): C[m][n] = sum_k xb[m][k]*wcat[n][k] + biascat[n], bf16 out.
// 256x256 tile, BK=64, 512 threads (8 waves, 2Mx4N), 128 KiB LDS double-buffer,
// 8-phase schedule with counted vmcnt(4), swizzled LDS (chunk ^= row&7, applied
// inverse on the global source since global_load_lds writes linearly), setprio
// around MFMA clusters, bijective XCD block swizzle. M=8192, N=2048, K=512
// (8 K-tiles = 3 steady iterations + 1 peeled). Accumulation order per C
// element is identical to R6 (k ascending) -> bitwise-same output.
// ---------------------------------------------------------------------------
template<int MH, int KK>
__device__ __forceinline__ void mm16(const short8 (&a)[4], const short8 (&b)[2][4],
                                     f32x4 (&acc)[8][4])
{
    #pragma unroll
    for (int f = 0; f < 4; ++f)
        #pragma unroll
        for (int g = 0; g < 4; ++g)
            acc[MH * 4 + f][g] = __builtin_amdgcn_mfma_f32_16x16x32_bf16(
                a[f], b[KK][g], acc[MH * 4 + f][g], 0, 0, 0);
}

template<int SLOT, int MH>
__device__ __forceinline__ void lda4(short8 (&a)[4], const u16* sm, int arow, int koff)
{
    #pragma unroll
    for (int f = 0; f < 4; ++f)
        a[f] = *(const short8*)(sm + SLOT * 32768 + (arow + MH * 64 + f * 16) * 64 + koff);
}

template<int SLOT>
__device__ __forceinline__ void ldb4(short8 (&bk)[4], const u16* sm, int brow, int koff)
{
    #pragma unroll
    for (int g = 0; g < 4; ++g)
        bk[g] = *(const short8*)(sm + SLOT * 32768 + 16384 + (brow + g * 16) * 64 + koff);
}

#define STA(S, CI, T) __builtin_amdgcn_global_load_lds( \
    (const __attribute__((address_space(1))) void*)(Ag + (size_t)(CI) * 32768 + (T) * 64), \
    (__attribute__((address_space(3))) void*)(sm + (S) * 32768 + (CI) * 4096 + wid * 512), 16, 0, 0)
#define STB(S, CI, T) __builtin_amdgcn_global_load_lds( \
    (const __attribute__((address_space(1))) void*)(Bg + (size_t)(CI) * 32768 + (T) * 64), \
    (__attribute__((address_space(3))) void*)(sm + (S) * 32768 + 16384 + (CI) * 4096 + wid * 512), 16, 0, 0)
#define KBAR()  __builtin_amdgcn_s_barrier()
#define KPRIO(P) __builtin_amdgcn_s_setprio(P)
#define LGKM0() do { asm volatile("s_waitcnt lgkmcnt(0)" ::: "memory"); \
                     __builtin_amdgcn_sched_barrier(0); } while (0)
#define VMC4()  asm volatile("s_waitcnt vmcnt(4)" ::: "memory")
#define VMC0()  asm volatile("s_waitcnt vmcnt(0)" ::: "memory")

__global__ __launch_bounds__(512, 2) void kqv_gemm_k(
    const u16* __restrict__ A, const u16* __restrict__ W,
    const float* __restrict__ bias, u16* __restrict__ C)
{
    __shared__ u16 sm[65536];   // 128 KiB: [slot][A 16384 | B 16384] u16

    const int bid = blockIdx.x;
    const int wg  = (bid & 7) * 32 + (bid >> 3);   // bijective XCD swizzle (256 = 8*32)
    const int bm  = (wg & 31) * 256;               // 32 M-tiles
    const int bn  = (wg >> 5) * 256;               // 8 N-tiles (one per XCD)
    const int tid  = threadIdx.x;
    const int wid  = tid >> 6;
    const int lane = tid & 63;
    const int l15  = lane & 15;
    const int quad = lane >> 4;
    const int wm = wid >> 2;    // 0..1
    const int wn = wid & 3;     // 0..3

    // staging: chunk = 64 rows x 64 u16 (8 KB) = 1 global_load_lds/thread.
    // LDS dest linear; source k-chunk pre-swizzled with (row&7) so that the
    // swizzled read below sees the right data (involution on chunk bits).
    const int stgrow = wid * 8 + (lane >> 3);                  // row within chunk
    const int stgk   = ((lane & 7) ^ ((lane >> 3) & 7)) << 3;  // swizzled 16B chunk
    const u16* Ag = A + (size_t)(bm + stgrow) * 512 + stgk;
    const u16* Bg = W + (size_t)(bn + stgrow) * 512 + stgk;

    const int r7     = l15 & 7;
    const int arow   = wm * 128 + l15;
    const int brow   = wn * 64 + l15;
    const int off_k0 = ((quad ^ r7) << 3);          // kf=0 swizzled 16B chunk
    const int off_k1 = (((4 | quad) ^ r7) << 3);    // kf=1

    f32x4 acc[8][4] = {};
    short8 a[4], b[2][4];

    // prologue: tile0 full (oldest 8 loads) + tile1 {a0,a2,b0,b1}
    STA(0,0,0); STA(0,2,0); STB(0,0,0); STB(0,1,0);
    STB(0,2,0); STB(0,3,0); STA(0,1,0); STA(0,3,0);
    STA(1,0,1); STA(1,2,1); STB(1,0,1); STB(1,1,1);
    VMC4(); KBAR();

    for (int it = 0; it < 3; ++it) {
        const int t = 2 * it;
        // ph1 (slot0, mh0, kf0); stage B(t+1) b2,b3 -> slot1
        ldb4<0>(b[0], sm, brow, off_k0); lda4<0,0>(a, sm, arow, off_k0);
        STB(1,2,t+1); STB(1,3,t+1);
        KBAR(); LGKM0(); KPRIO(1); mm16<0,0>(a, b, acc); KPRIO(0); KBAR();
        // ph2 (slot0, mh0, kf1); stage A(t+1) a1,a3 -> slot1
        ldb4<0>(b[1], sm, brow, off_k1); lda4<0,0>(a, sm, arow, off_k1);
        STA(1,1,t+1); STA(1,3,t+1);
        KBAR(); LGKM0(); KPRIO(1); mm16<0,1>(a, b, acc); KPRIO(0); KBAR();
        // ph3 (slot0, mh1, kf0); stage A(t+2) a0,a2 -> slot0 (A-mh0 free since ph2)
        lda4<0,1>(a, sm, arow, off_k0);
        STA(0,0,t+2); STA(0,2,t+2);
        KBAR(); LGKM0(); KPRIO(1); mm16<1,0>(a, b, acc); KPRIO(0); KBAR();
        // ph4 (slot0, mh1, kf1); stage B(t+2) b0,b1; vmcnt(4) -> tile t+1 landed
        lda4<0,1>(a, sm, arow, off_k1);
        STB(0,0,t+2); STB(0,1,t+2);
        KBAR(); LGKM0(); KPRIO(1); mm16<1,1>(a, b, acc); KPRIO(0); VMC4(); KBAR();
        // ph5 (slot1, mh0, kf0); stage B(t+2) b2,b3 -> slot0
        ldb4<1>(b[0], sm, brow, off_k0); lda4<1,0>(a, sm, arow, off_k0);
        STB(0,2,t+2); STB(0,3,t+2);
        KBAR(); LGKM0(); KPRIO(1); mm16<0,0>(a, b, acc); KPRIO(0); KBAR();
        // ph6 (slot1, mh0, kf1); stage A(t+2) a1,a3 -> slot0 (A-mh1 free since ph4)
        ldb4<1>(b[1], sm, brow, off_k1); lda4<1,0>(a, sm, arow, off_k1);
        STA(0,1,t+2); STA(0,3,t+2);
        KBAR(); LGKM0(); KPRIO(1); mm16<0,1>(a, b, acc); KPRIO(0); KBAR();
        // ph7 (slot1, mh1, kf0); stage A(t+3) a0,a2 -> slot1 (free since ph6)
        lda4<1,1>(a, sm, arow, off_k0);
        STA(1,0,t+3); STA(1,2,t+3);
        KBAR(); LGKM0(); KPRIO(1); mm16<1,0>(a, b, acc); KPRIO(0); KBAR();
        // ph8 (slot1, mh1, kf1); stage B(t+3) b0,b1 -> slot1; vmcnt(4) -> t+2 landed
        lda4<1,1>(a, sm, arow, off_k1);
        STB(1,0,t+3); STB(1,1,t+3);
        KBAR(); LGKM0(); KPRIO(1); mm16<1,1>(a, b, acc); KPRIO(0); VMC4(); KBAR();
    }

    // peeled last iteration: tiles 6 (slot0) / 7 (slot1); finish tile7 staging,
    // single vmcnt(0) at ph4, no further stages.
    ldb4<0>(b[0], sm, brow, off_k0); lda4<0,0>(a, sm, arow, off_k0);
    STB(1,2,7); STB(1,3,7);
    KBAR(); LGKM0(); KPRIO(1); mm16<0,0>(a, b, acc); KPRIO(0); KBAR();
    ldb4<0>(b[1], sm, brow, off_k1); lda4<0,0>(a, sm, arow, off_k1);
    STA(1,1,7); STA(1,3,7);
    KBAR(); LGKM0(); KPRIO(1); mm16<0,1>(a, b, acc); KPRIO(0); KBAR();
    lda4<0,1>(a, sm, arow, off_k0);
    KBAR(); LGKM0(); KPRIO(1); mm16<1,0>(a, b, acc); KPRIO(0); KBAR();
    lda4<0,1>(a, sm, arow, off_k1);
    KBAR(); LGKM0(); KPRIO(1); mm16<1,1>(a, b, acc); KPRIO(0); VMC0(); KBAR();
    ldb4<1>(b[0], sm, brow, off_k0); lda4<1,0>(a, sm, arow, off_k0);
    KBAR(); LGKM0(); KPRIO(1); mm16<0,0>(a, b, acc); KPRIO(0); KBAR();
    ldb4<1>(b[1], sm, brow, off_k1); lda4<1,0>(a, sm, arow, off_k1);
    KBAR(); LGKM0(); KPRIO(1); mm16<0,1>(a, b, acc); KPRIO(0); KBAR();
    lda4<1,1>(a, sm, arow, off_k0);
    KBAR(); LGKM0(); KPRIO(1); mm16<1,0>(a, b, acc); KPRIO(0); KBAR();
    lda4<1,1>(a, sm, arow, off_k1);
    KBAR(); LGKM0(); KPRIO(1); mm16<1,1>(a, b, acc); KPRIO(0);

    // epilogue: bias + bf16 round + store (same pattern as R6)
    #pragma unroll
    for (int mf = 0; mf < 8; ++mf) {
        #pragma unroll
        for (int g = 0; g < 4; ++g) {
            const int col = bn + wn * 64 + g * 16 + l15;
            const float bvv = bias[col];
            #pragma unroll
            for (int r = 0; r < 4; ++r) {
                const int row = bm + wm * 128 + mf * 16 + quad * 4 + r;
                C[(size_t)row * LDK + col] = f2b(acc[mf][g][r] + bvv);
            }
        }
    }
}

#undef STA
#undef STB
#undef KBAR
#undef KPRIO
#undef LGKM0
#undef VMC4
#undef VMC0

// ---------------------------------------------------------------------------
// heads: grid (32 blk, 4 b, 4 e-chunk).
//  Phase A (LDS-staged, BK=64): S1 = K_blk.Q_blk^T (64x64), S2 = K_blk.Qsel^T
//  (64x32), K=512; masks c<=r / m<=blk; S -> smA bf16.
//  Phase B: out[:, e0:+128] = [S1|S2] @ [VU1_blk ; VU2sel]^T + bu (K=96).
// ---------------------------------------------------------------------------
__global__ __launch_bounds__(256) void heads_k(
    const u16* __restrict__ KQV, const float* __restrict__ bu, float* __restrict__ out)
{
    __shared__ u16 smA[64 * 104];     // [row][0:64 S1 | 64:96 S2]
    __shared__ u16 smVT[128 * 104];   // [e][0:64 VU1^T | 64:96 VU2sel^T]
    __shared__ u16 pK[2][64 * 32];    // k-panels (BK=64 = 2 x 32)
    __shared__ u16 pQ[2][64 * 32];
    __shared__ u16 pQs[2][32 * 32];

    const int blk = blockIdx.x, b = blockIdx.y;
    const int e0 = blockIdx.z * 128;
    const int tid = threadIdx.x;
    const int wid = tid >> 6, lane = tid & 63;
    const int l15 = lane & 15, quad = lane >> 4;
    const size_t row0 = (size_t)b * TDIM + (size_t)blk * 64;
    const size_t brow = (size_t)b * TDIM;
    const int srow_base = 16 * wid + quad * 4;

    // ---- VU^T staging (independent of S; overlaps Phase A latency) ----
    #pragma unroll
    for (int it = 0; it < 4; ++it) {
        const int id = tid + 256 * it;
        const int c  = id & 63;
        const int eo = (id >> 6) * 8;
        short8 v = *(const short8*)(KQV + (row0 + c) * (size_t)LDK + 1024 + e0 + eo);
        #pragma unroll
        for (int i = 0; i < 8; ++i) smVT[(eo + i) * 104 + c] = (u16)v[i];
    }
    #pragma unroll
    for (int it = 0; it < 2; ++it) {
        const int id = tid + 256 * it;
        const int m  = id & 31;
        const int eo = (id >> 5) * 8;
        short8 v = *(const short8*)(KQV + (brow + 64 * m) * (size_t)LDK + 1536 + e0 + eo);
        #pragma unroll
        for (int i = 0; i < 8; ++i) smVT[(eo + i) * 104 + 64 + m] = (u16)v[i];
    }

    // ---- Phase A ----
    f32x4 s1[4] = {}; f32x4 s2[2] = {};
    const int srow  = tid >> 2;
    const int skoff = (tid & 3) * 8;
    const int qsrow = srow & 31;
    const int qsp   = tid >> 7;
    const u16* Kg  = KQV + (row0 + srow) * (size_t)LDK + skoff;
    const u16* Qg  = KQV + (row0 + srow) * (size_t)LDK + 512 + skoff;
    const u16* Qsg = KQV + (brow + (size_t)64 * qsrow) * (size_t)LDK + 512 + qsp * 32 + skoff;
    char* dK  = (char*)pK  + wid * 1024;
    char* dQ  = (char*)pQ  + wid * 1024;
    char* dQs = (char*)pQs + wid * 1024;

    for (int k0 = 0; k0 < 512; k0 += 64) {
        __syncthreads();
        __builtin_amdgcn_global_load_lds(
            (const __attribute__((address_space(1))) void*)(Kg + k0),
            (__attribute__((address_space(3))) void*)dK, 16, 0, 0);
        __builtin_amdgcn_global_load_lds(
            (const __attribute__((address_space(1))) void*)(Kg + k0 + 32),
            (__attribute__((address_space(3))) void*)(dK + 4096), 16, 0, 0);
        __builtin_amdgcn_global_load_lds(
            (const __attribute__((address_space(1))) void*)(Qg + k0),
            (__attribute__((address_space(3))) void*)dQ, 16, 0, 0);
        __builtin_amdgcn_global_load_lds(
            (const __attribute__((address_space(1))) void*)(Qg + k0 + 32),
            (__attribute__((address_space(3))) void*)(dQ + 4096), 16, 0, 0);
        __builtin_amdgcn_global_load_lds(
            (const __attribute__((address_space(1))) void*)(Qsg + k0),
            (__attribute__((address_space(3))) void*)dQs, 16, 0, 0);
        __syncthreads();

        short8 a0 = *(const short8*)(pK[0] + (16 * wid + l15) * 32 + quad * 8);
        short8 a1 = *(const short8*)(pK[1] + (16 * wid + l15) * 32 + quad * 8);
        #pragma unroll
        for (int j = 0; j < 4; ++j) {
            short8 b0 = *(const short8*)(pQ[0] + (16 * j + l15) * 32 + quad * 8);
            short8 b1 = *(const short8*)(pQ[1] + (16 * j + l15) * 32 + quad * 8);
            s1[j] = __builtin_amdgcn_mfma_f32_16x16x32_bf16(a0, b0, s1[j], 0, 0, 0);
            s1[j] = __builtin_amdgcn_mfma_f32_16x16x32_bf16(a1, b1, s1[j], 0, 0, 0);
        }
        #pragma unroll
        for (int j = 0; j < 2; ++j) {
            short8 b0 = *(const short8*)(pQs[0] + (16 * j + l15) * 32 + quad * 8);
            short8 b1 = *(const short8*)(pQs[1] + (16 * j + l15) * 32 + quad * 8);
            s2[j] = __builtin_amdgcn_mfma_f32_16x16x32_bf16(a0, b0, s2[j], 0, 0, 0);
            s2[j] = __builtin_amdgcn_mfma_f32_16x16x32_bf16(a1, b1, s2[j], 0, 0, 0);
        }
    }

    #pragma unroll
    for (int j = 0; j < 4; ++j)
        #pragma unroll
        for (int r = 0; r < 4; ++r) {
            const int rr = srow_base + r;
            const int cc = 16 * j + l15;
            smA[rr * 104 + cc] = f2b((cc <= rr) ? s1[j][r] : 0.0f);
        }
    #pragma unroll
    for (int j = 0; j < 2; ++j)
        #pragma unroll
        for (int r = 0; r < 4; ++r) {
            const int m  = 16 * j + l15;
            const int rr = srow_base + r;
            smA[rr * 104 + 64 + m] = f2b((m <= blk) ? s2[j][r] : 0.0f);
        }
    __syncthreads();

    // ---- Phase B: out = [S1|S2] @ smVT^T  (K=96, N=128) ----
    f32x4 o[8] = {};
    const u16* arow = smA + (16 * wid + l15) * 104;
    #pragma unroll
    for (int ks = 0; ks < 3; ++ks) {
        short8 as = *(const short8*)(arow + 32 * ks + quad * 8);
        #pragma unroll
        for (int nt = 0; nt < 8; ++nt) {
            short8 bs = *(const short8*)(smVT + (16 * nt + l15) * 104 + 32 * ks + quad * 8);
            o[nt] = __builtin_amdgcn_mfma_f32_16x16x32_bf16(as, bs, o[nt], 0, 0, 0);
        }
    }
    #pragma unroll
    for (int nt = 0; nt < 8; ++nt) {
        const int col = e0 + 16 * nt + l15;
        const float bvv = bu[col];
        #pragma unroll
        for (int r = 0; r < 4; ++r)
            out[(row0 + srow_base + r) * (size_t)EMB_D + col] = o[nt][r] + bvv;
    }
}

extern "C" void kernel_launch(void* const* d_in, const int* in_sizes, int n_in,
                              void* d_out, int out_size, void* d_ws, size_t ws_size,
                              hipStream_t stream)
{
    const float* x  = (const float*)d_in[0];
    const float* Wk = (const float*)d_in[1];
    const float* bk = (const float*)d_in[2];
    const float* Wq = (const float*)d_in[3];
    const float* bq = (const float*)d_in[4];
    const float* Wv = (const float*)d_in[5];
    const float* bv = (const float*)d_in[6];
    const float* Wu = (const float*)d_in[7];
    const float* bu = (const float*)d_in[8];
    float* out = (float*)d_out;

    char* w = (char*)d_ws;
    u16*   KQV     = (u16*)  (w + ((size_t)0  << 20));
    u16*   xb      = (u16*)  (w + ((size_t)32 << 20));
    u16*   wcat    = (u16*)  (w + ((size_t)40 << 20));
    u16*   wvtb    = (u16*)  (w + ((size_t)42 << 20));
    u16*   wub     = (u16*)  (w + ((size_t)43 << 20));
    float* biascat = (float*)(w + ((size_t)44 << 20));

    hipLaunchKernelGGL(prep_k, dim3(5201), dim3(256), 0, stream,
                       x, Wk, Wq, Wv, Wu, bk, bq, bv, xb, wcat, wvtb, wub, biascat);
    hipLaunchKernelGGL(wc_gemm_k, dim3(8, 4), dim3(256), 0, stream, wub, wvtb, wcat);
    hipLaunchKernelGGL(kqv_gemm_k, dim3(256), dim3(512), 0, stream, xb, wcat, biascat, KQV);
    hipLaunchKernelGGL(heads_k, dim3(NBLK, BB, 4), dim3(256), 0, stream, KQV, bu, out);
}

// Round 2
// 141.616 us; speedup vs baseline: 1.0523x; 1.0196x over previous
//
#include <hip/hip_runtime.h>

// BlocksparseFixedSelfAttention: B=4, T=2048, EMB=512, KBLK=64.
// R8: wc_gemm folded into prep_k as direct-fp32 MFMA blocks (bid 0..31, run
// first, overlap the BW-bound casts; wub/wvtb eliminated) -> 3 launches.
// kqv epilogue: LDS-repack of the 256x256 C tile -> coalesced dwordx4 stores.
// kqv core = R7 8-phase (m201 template). heads unchanged.
// ws (MB): KQV bf16 32 @0 | xb 8 @32 | wcat bf16 2048x512 @40 | biascat @44

typedef unsigned short u16;
typedef __attribute__((ext_vector_type(8))) short short8;
typedef __attribute__((ext_vector_type(4))) float f32x4;

constexpr int TDIM  = 2048;
constexpr int EMB_D = 512;
constexpr int BB    = 4;
constexpr int NBLK  = 32;    // T / 64
constexpr int LDK   = 2048;  // KQV row stride (u16)

__device__ __forceinline__ u16 f2b(float f) {
    unsigned u = __float_as_uint(f);
    unsigned r = (u + 0x7FFFu + ((u >> 16) & 1u)) >> 16;
    return (u16)r;
}

// ---------------------------------------------------------------------------
// prep (one launch, all parts independent):
//  [0,32)      Wc MFMA blocks: wcat rows 1024+m = Wu2 @ Wv  (fp32 sources,
//              f2b in-register -> bitwise-identical to the old wub/wvtb path)
//  [32,4128)   cast x -> xb
//  [4128,4384) cast Wk -> wcat[0:512]
//  [4384,4640) cast Wq -> wcat[512:1024]
//  [4640,4656) biascat[1024+o] = Wu[o&511][.] . bv  (4 lanes/output + shfl)
//  4656        biascat[0:1024] = [bk|bq]
// ---------------------------------------------------------------------------
__global__ __launch_bounds__(256) void prep_k(
    const float* __restrict__ x, const float* __restrict__ Wk, const float* __restrict__ Wq,
    const float* __restrict__ Wv, const float* __restrict__ Wu,
    const float* __restrict__ bk, const float* __restrict__ bq, const float* __restrict__ bv,
    u16* __restrict__ xb, u16* __restrict__ wcat, float* __restrict__ biascat)
{
    const int bid = blockIdx.x, tid = threadIdx.x;
    if (bid < 32) {
        // Wc[m][k] = sum_j Wu2[m][j] * Wv[j][k];  Wu2[m][j] = Wu[m&511][(m>>9)*512+j]
        // 128x128 tile, BJ=32, no LDS: fragments gathered from global fp32 + f2b.
        // Same j-step order / same MFMA sequence as the old wc_gemm -> bitwise equal.
        const int bm = (bid >> 2) * 128;   // M = 1024
        const int bn = (bid & 3) * 128;    // N = 512 (the k-dim of Wc)
        const int wid  = tid >> 6;
        const int lane = tid & 63;
        const int l15  = lane & 15;
        const int quad = lane >> 4;
        const int wm = (wid & 1) * 64;
        const int wn = (wid >> 1) * 64;

        f32x4 acc[4][4] = {};

        const float* Arow[4];
        #pragma unroll
        for (int i = 0; i < 4; ++i) {
            const int m = bm + wm + 16 * i + l15;
            Arow[i] = Wu + (size_t)(m & 511) * 1024 + (m >> 9) * 512 + quad * 8;
        }
        const float* Bcol[4];
        #pragma unroll
        for (int g = 0; g < 4; ++g)
            Bcol[g] = Wv + (bn + wn + 16 * g + l15) + (size_t)(quad * 8) * 512;

        for (int j0 = 0; j0 < 512; j0 += 32) {
            short8 a[4], b[4];
            #pragma unroll
            for (int i = 0; i < 4; ++i) {
                float4 v0 = *(const float4*)(Arow[i] + j0);
                float4 v1 = *(const float4*)(Arow[i] + j0 + 4);
                a[i] = (short8){(short)f2b(v0.x), (short)f2b(v0.y), (short)f2b(v0.z), (short)f2b(v0.w),
                                (short)f2b(v1.x), (short)f2b(v1.y), (short)f2b(v1.z), (short)f2b(v1.w)};
            }
            #pragma unroll
            for (int g = 0; g < 4; ++g) {
                const float* p = Bcol[g] + (size_t)j0 * 512;
                float v0 = p[0];          float v1 = p[512];
                float v2 = p[1024];       float v3 = p[1536];
                float v4 = p[2048];       float v5 = p[2560];
                float v6 = p[3072];       float v7 = p[3584];
                b[g] = (short8){(short)f2b(v0), (short)f2b(v1), (short)f2b(v2), (short)f2b(v3),
                                (short)f2b(v4), (short)f2b(v5), (short)f2b(v6), (short)f2b(v7)};
            }
            #pragma unroll
            for (int i = 0; i < 4; ++i)
                #pragma unroll
                for (int g = 0; g < 4; ++g)
                    acc[i][g] = __builtin_amdgcn_mfma_f32_16x16x32_bf16(a[i], b[g], acc[i][g], 0, 0, 0);
        }

        #pragma unroll
        for (int i = 0; i < 4; ++i)
            #pragma unroll
            for (int g = 0; g < 4; ++g) {
                const int col = bn + wn + 16 * g + l15;
                #pragma unroll
                for (int r = 0; r < 4; ++r) {
                    const int row = bm + wm + 16 * i + quad * 4 + r;
                    wcat[(size_t)(1024 + row) * 512 + col] = f2b(acc[i][g][r]);
                }
            }
    } else if (bid < 4640) {
        const float* src; u16* dst; int base;
        if (bid < 4128)      { src = x;  dst = xb;            base = (bid - 32) * 1024; }
        else if (bid < 4384) { src = Wk; dst = wcat;          base = (bid - 4128) * 1024; }
        else                 { src = Wq; dst = wcat + 262144; base = (bid - 4384) * 1024; }
        const int idx = base + tid * 4;
        float4 v = *(const float4*)(src + idx);
        ushort4 o = { f2b(v.x), f2b(v.y), f2b(v.z), f2b(v.w) };
        *(ushort4*)(dst + idx) = o;
    } else if (bid < 4656) {
        // Wu.bv dot: output o = (bid-4640)*64 + tid/4, lane-part p = tid%4
        const int o = (bid - 4640) * 64 + (tid >> 2);
        const int p = tid & 3;
        const int n = o & 511, half = o >> 9;
        const float* wr = Wu + (size_t)n * 1024 + half * 512 + p * 128;
        const float* br = bv + p * 128;
        float s = 0.f;
        #pragma unroll
        for (int j = 0; j < 128; j += 4) {
            float4 a = *(const float4*)(wr + j);
            float4 b = *(const float4*)(br + j);
            s += a.x*b.x + a.y*b.y + a.z*b.z + a.w*b.w;
        }
        s += __shfl_xor(s, 1);
        s += __shfl_xor(s, 2);
        if (p == 0) biascat[1024 + o] = s;
    } else {
        const int idx = tid * 4;
        float4 v = (idx < 512) ? *(const float4*)(bk + idx)
                               : *(const float4*)(bq + idx - 512);
        *(float4*)(biascat + idx) = v;
    }
}

// ---------------------------------------------------------------------------
// KQV GEMM: C[m][n] = sum_k xb[m][k]*wcat[n][k] + biascat[n], bf16 out.
// 256x256 tile, BK=64, 512 threads (8 waves, 2Mx4N), 128 KiB LDS double-buffer,
// 8-phase schedule with counted vmcnt(4), swizzled LDS reads (inverse swizzle
// on the global source since global_load_lds writes linearly), setprio around
// MFMA clusters, bijective XCD block swizzle. M=8192, N=2048, K=512
// (8 K-tiles = 3 steady iterations + 1 peeled). Epilogue (R8): repack the
// 256x256 C tile through the (now free) 128 KiB LDS -> dwordx4 stores.
// ---------------------------------------------------------------------------
template<int MH, int KK>
__device__ __forceinline__ void mm16(const short8 (&a)[4], const short8 (&b)[2][4],
                                     f32x4 (&acc)[8][4])
{
    #pragma unroll
    for (int f = 0; f < 4; ++f)
        #pragma unroll
        for (int g = 0; g < 4; ++g)
            acc[MH * 4 + f][g] = __builtin_amdgcn_mfma_f32_16x16x32_bf16(
                a[f], b[KK][g], acc[MH * 4 + f][g], 0, 0, 0);
}

template<int SLOT, int MH>
__device__ __forceinline__ void lda4(short8 (&a)[4], const u16* sm, int arow, int koff)
{
    #pragma unroll
    for (int f = 0; f < 4; ++f)
        a[f] = *(const short8*)(sm + SLOT * 32768 + (arow + MH * 64 + f * 16) * 64 + koff);
}

template<int SLOT>
__device__ __forceinline__ void ldb4(short8 (&bk)[4], const u16* sm, int brow, int koff)
{
    #pragma unroll
    for (int g = 0; g < 4; ++g)
        bk[g] = *(const short8*)(sm + SLOT * 32768 + 16384 + (brow + g * 16) * 64 + koff);
}

#define STA(S, CI, T) __builtin_amdgcn_global_load_lds( \
    (const __attribute__((address_space(1))) void*)(Ag + (size_t)(CI) * 32768 + (T) * 64), \
    (__attribute__((address_space(3))) void*)(sm + (S) * 32768 + (CI) * 4096 + wid * 512), 16, 0, 0)
#define STB(S, CI, T) __builtin_amdgcn_global_load_lds( \
    (const __attribute__((address_space(1))) void*)(Bg + (size_t)(CI) * 32768 + (T) * 64), \
    (__attribute__((address_space(3))) void*)(sm + (S) * 32768 + 16384 + (CI) * 4096 + wid * 512), 16, 0, 0)
#define KBAR()  __builtin_amdgcn_s_barrier()
#define KPRIO(P) __builtin_amdgcn_s_setprio(P)
#define LGKM0() do { asm volatile("s_waitcnt lgkmcnt(0)" ::: "memory"); \
                     __builtin_amdgcn_sched_barrier(0); } while (0)
#define VMC4()  asm volatile("s_waitcnt vmcnt(4)" ::: "memory")
#define VMC0()  asm volatile("s_waitcnt vmcnt(0)" ::: "memory")

__global__ __launch_bounds__(512, 2) void kqv_gemm_k(
    const u16* __restrict__ A, const u16* __restrict__ W,
    const float* __restrict__ bias, u16* __restrict__ C)
{
    __shared__ u16 sm[65536];   // 128 KiB: [slot][A 16384 | B 16384] u16

    const int bid = blockIdx.x;
    const int wg  = (bid & 7) * 32 + (bid >> 3);   // bijective XCD swizzle (256 = 8*32)
    const int bm  = (wg & 31) * 256;               // 32 M-tiles
    const int bn  = (wg >> 5) * 256;               // 8 N-tiles (one per XCD)
    const int tid  = threadIdx.x;
    const int wid  = tid >> 6;
    const int lane = tid & 63;
    const int l15  = lane & 15;
    const int quad = lane >> 4;
    const int wm = wid >> 2;    // 0..1
    const int wn = wid & 3;     // 0..3

    // staging: chunk = 64 rows x 64 u16 (8 KB) = 1 global_load_lds/thread.
    // LDS dest linear; source k-chunk pre-swizzled with (row&7) so that the
    // swizzled read below sees the right data (involution on chunk bits).
    const int stgrow = wid * 8 + (lane >> 3);                  // row within chunk
    const int stgk   = ((lane & 7) ^ ((lane >> 3) & 7)) << 3;  // swizzled 16B chunk
    const u16* Ag = A + (size_t)(bm + stgrow) * 512 + stgk;
    const u16* Bg = W + (size_t)(bn + stgrow) * 512 + stgk;

    const int r7     = l15 & 7;
    const int arow   = wm * 128 + l15;
    const int brow   = wn * 64 + l15;
    const int off_k0 = ((quad ^ r7) << 3);          // kf=0 swizzled 16B chunk
    const int off_k1 = (((4 | quad) ^ r7) << 3);    // kf=1

    f32x4 acc[8][4] = {};
    short8 a[4], b[2][4];

    // prologue: tile0 full (oldest 8 loads) + tile1 {a0,a2,b0,b1}
    STA(0,0,0); STA(0,2,0); STB(0,0,0); STB(0,1,0);
    STB(0,2,0); STB(0,3,0); STA(0,1,0); STA(0,3,0);
    STA(1,0,1); STA(1,2,1); STB(1,0,1); STB(1,1,1);
    VMC4(); KBAR();

    for (int it = 0; it < 3; ++it) {
        const int t = 2 * it;
        // ph1 (slot0, mh0, kf0); stage B(t+1) b2,b3 -> slot1
        ldb4<0>(b[0], sm, brow, off_k0); lda4<0,0>(a, sm, arow, off_k0);
        STB(1,2,t+1); STB(1,3,t+1);
        KBAR(); LGKM0(); KPRIO(1); mm16<0,0>(a, b, acc); KPRIO(0); KBAR();
        // ph2 (slot0, mh0, kf1); stage A(t+1) a1,a3 -> slot1
        ldb4<0>(b[1], sm, brow, off_k1); lda4<0,0>(a, sm, arow, off_k1);
        STA(1,1,t+1); STA(1,3,t+1);
        KBAR(); LGKM0(); KPRIO(1); mm16<0,1>(a, b, acc); KPRIO(0); KBAR();
        // ph3 (slot0, mh1, kf0); stage A(t+2) a0,a2 -> slot0 (A-mh0 free since ph2)
        lda4<0,1>(a, sm, arow, off_k0);
        STA(0,0,t+2); STA(0,2,t+2);
        KBAR(); LGKM0(); KPRIO(1); mm16<1,0>(a, b, acc); KPRIO(0); KBAR();
        // ph4 (slot0, mh1, kf1); stage B(t+2) b0,b1; vmcnt(4) -> tile t+1 landed
        lda4<0,1>(a, sm, arow, off_k1);
        STB(0,0,t+2); STB(0,1,t+2);
        KBAR(); LGKM0(); KPRIO(1); mm16<1,1>(a, b, acc); KPRIO(0); VMC4(); KBAR();
        // ph5 (slot1, mh0, kf0); stage B(t+2) b2,b3 -> slot0
        ldb4<1>(b[0], sm, brow, off_k0); lda4<1,0>(a, sm, arow, off_k0);
        STB(0,2,t+2); STB(0,3,t+2);
        KBAR(); LGKM0(); KPRIO(1); mm16<0,0>(a, b, acc); KPRIO(0); KBAR();
        // ph6 (slot1, mh0, kf1); stage A(t+2) a1,a3 -> slot0 (A-mh1 free since ph4)
        ldb4<1>(b[1], sm, brow, off_k1); lda4<1,0>(a, sm, arow, off_k1);
        STA(0,1,t+2); STA(0,3,t+2);
        KBAR(); LGKM0(); KPRIO(1); mm16<0,1>(a, b, acc); KPRIO(0); KBAR();
        // ph7 (slot1, mh1, kf0); stage A(t+3) a0,a2 -> slot1 (free since ph6)
        lda4<1,1>(a, sm, arow, off_k0);
        STA(1,0,t+3); STA(1,2,t+3);
        KBAR(); LGKM0(); KPRIO(1); mm16<1,0>(a, b, acc); KPRIO(0); KBAR();
        // ph8 (slot1, mh1, kf1); stage B(t+3) b0,b1 -> slot1; vmcnt(4) -> t+2 landed
        lda4<1,1>(a, sm, arow, off_k1);
        STB(1,0,t+3); STB(1,1,t+3);
        KBAR(); LGKM0(); KPRIO(1); mm16<1,1>(a, b, acc); KPRIO(0); VMC4(); KBAR();
    }

    // peeled last iteration: tiles 6 (slot0) / 7 (slot1); finish tile7 staging,
    // single vmcnt(0) at ph4, no further stages.
    ldb4<0>(b[0], sm, brow, off_k0); lda4<0,0>(a, sm, arow, off_k0);
    STB(1,2,7); STB(1,3,7);
    KBAR(); LGKM0(); KPRIO(1); mm16<0,0>(a, b, acc); KPRIO(0); KBAR();
    ldb4<0>(b[1], sm, brow, off_k1); lda4<0,0>(a, sm, arow, off_k1);
    STA(1,1,7); STA(1,3,7);
    KBAR(); LGKM0(); KPRIO(1); mm16<0,1>(a, b, acc); KPRIO(0); KBAR();
    lda4<0,1>(a, sm, arow, off_k0);
    KBAR(); LGKM0(); KPRIO(1); mm16<1,0>(a, b, acc); KPRIO(0); KBAR();
    lda4<0,1>(a, sm, arow, off_k1);
    KBAR(); LGKM0(); KPRIO(1); mm16<1,1>(a, b, acc); KPRIO(0); VMC0(); KBAR();
    ldb4<1>(b[0], sm, brow, off_k0); lda4<1,0>(a, sm, arow, off_k0);
    KBAR(); LGKM0(); KPRIO(1); mm16<0,0>(a, b, acc); KPRIO(0); KBAR();
    ldb4<1>(b[1], sm, brow, off_k1); lda4<1,0>(a, sm, arow, off_k1);
    KBAR(); LGKM0(); KPRIO(1); mm16<0,1>(a, b, acc); KPRIO(0); KBAR();
    lda4<1,1>(a, sm, arow, off_k0);
    KBAR(); LGKM0(); KPRIO(1); mm16<1,0>(a, b, acc); KPRIO(0); KBAR();
    lda4<1,1>(a, sm, arow, off_k1);
    KBAR(); LGKM0(); KPRIO(1); mm16<1,1>(a, b, acc); KPRIO(0);

    // epilogue (R8): bias + bf16 round -> LDS [256][256] u16 -> coalesced
    // dwordx4 stores. __syncthreads (full fence) before reusing sm: other
    // waves may still be ds_reading slot1.
    __syncthreads();
    #pragma unroll
    for (int mf = 0; mf < 8; ++mf) {
        #pragma unroll
        for (int g = 0; g < 4; ++g) {
            const int col = wn * 64 + g * 16 + l15;
            const float bvv = bias[bn + col];
            #pragma unroll
            for (int r = 0; r < 4; ++r) {
                const int row = wm * 128 + mf * 16 + quad * 4 + r;
                sm[row * 256 + col] = f2b(acc[mf][g][r] + bvv);
            }
        }
    }
    __syncthreads();
    {
        const int rr = tid >> 5;          // 0..15
        const int ck = tid & 31;          // 0..31 (16B col chunks)
        #pragma unroll
        for (int p = 0; p < 16; ++p) {
            const int row = p * 16 + rr;
            short8 v = *(const short8*)(sm + row * 256 + ck * 8);
            *(short8*)(C + (size_t)(bm + row) * LDK + bn + ck * 8) = v;
        }
    }
}

#undef STA
#undef STB
#undef KBAR
#undef KPRIO
#undef LGKM0
#undef VMC4
#undef VMC0

// ---------------------------------------------------------------------------
// heads: grid (32 blk, 4 b, 4 e-chunk).
//  Phase A (LDS-staged, BK=64): S1 = K_blk.Q_blk^T (64x64), S2 = K_blk.Qsel^T
//  (64x32), K=512; masks c<=r / m<=blk; S -> smA bf16.
//  Phase B: out[:, e0:+128] = [S1|S2] @ [VU1_blk ; VU2sel]^T + bu (K=96).
// ---------------------------------------------------------------------------
__global__ __launch_bounds__(256) void heads_k(
    const u16* __restrict__ KQV, const float* __restrict__ bu, float* __restrict__ out)
{
    __shared__ u16 smA[64 * 104];     // [row][0:64 S1 | 64:96 S2]
    __shared__ u16 smVT[128 * 104];   // [e][0:64 VU1^T | 64:96 VU2sel^T]
    __shared__ u16 pK[2][64 * 32];    // k-panels (BK=64 = 2 x 32)
    __shared__ u16 pQ[2][64 * 32];
    __shared__ u16 pQs[2][32 * 32];

    const int blk = blockIdx.x, b = blockIdx.y;
    const int e0 = blockIdx.z * 128;
    const int tid = threadIdx.x;
    const int wid = tid >> 6, lane = tid & 63;
    const int l15 = lane & 15, quad = lane >> 4;
    const size_t row0 = (size_t)b * TDIM + (size_t)blk * 64;
    const size_t brow = (size_t)b * TDIM;
    const int srow_base = 16 * wid + quad * 4;

    // ---- VU^T staging (independent of S; overlaps Phase A latency) ----
    #pragma unroll
    for (int it = 0; it < 4; ++it) {
        const int id = tid + 256 * it;
        const int c  = id & 63;
        const int eo = (id >> 6) * 8;
        short8 v = *(const short8*)(KQV + (row0 + c) * (size_t)LDK + 1024 + e0 + eo);
        #pragma unroll
        for (int i = 0; i < 8; ++i) smVT[(eo + i) * 104 + c] = (u16)v[i];
    }
    #pragma unroll
    for (int it = 0; it < 2; ++it) {
        const int id = tid + 256 * it;
        const int m  = id & 31;
        const int eo = (id >> 5) * 8;
        short8 v = *(const short8*)(KQV + (brow + 64 * m) * (size_t)LDK + 1536 + e0 + eo);
        #pragma unroll
        for (int i = 0; i < 8; ++i) smVT[(eo + i) * 104 + 64 + m] = (u16)v[i];
    }

    // ---- Phase A ----
    f32x4 s1[4] = {}; f32x4 s2[2] = {};
    const int srow  = tid >> 2;
    const int skoff = (tid & 3) * 8;
    const int qsrow = srow & 31;
    const int qsp   = tid >> 7;
    const u16* Kg  = KQV + (row0 + srow) * (size_t)LDK + skoff;
    const u16* Qg  = KQV + (row0 + srow) * (size_t)LDK + 512 + skoff;
    const u16* Qsg = KQV + (brow + (size_t)64 * qsrow) * (size_t)LDK + 512 + qsp * 32 + skoff;
    char* dK  = (char*)pK  + wid * 1024;
    char* dQ  = (char*)pQ  + wid * 1024;
    char* dQs = (char*)pQs + wid * 1024;

    for (int k0 = 0; k0 < 512; k0 += 64) {
        __syncthreads();
        __builtin_amdgcn_global_load_lds(
            (const __attribute__((address_space(1))) void*)(Kg + k0),
            (__attribute__((address_space(3))) void*)dK, 16, 0, 0);
        __builtin_amdgcn_global_load_lds(
            (const __attribute__((address_space(1))) void*)(Kg + k0 + 32),
            (__attribute__((address_space(3))) void*)(dK + 4096), 16, 0, 0);
        __builtin_amdgcn_global_load_lds(
            (const __attribute__((address_space(1))) void*)(Qg + k0),
            (__attribute__((address_space(3))) void*)dQ, 16, 0, 0);
        __builtin_amdgcn_global_load_lds(
            (const __attribute__((address_space(1))) void*)(Qg + k0 + 32),
            (__attribute__((address_space(3))) void*)(dQ + 4096), 16, 0, 0);
        __builtin_amdgcn_global_load_lds(
            (const __attribute__((address_space(1))) void*)(Qsg + k0),
            (__attribute__((address_space(3))) void*)dQs, 16, 0, 0);
        __syncthreads();

        short8 a0 = *(const short8*)(pK[0] + (16 * wid + l15) * 32 + quad * 8);
        short8 a1 = *(const short8*)(pK[1] + (16 * wid + l15) * 32 + quad * 8);
        #pragma unroll
        for (int j = 0; j < 4; ++j) {
            short8 b0 = *(const short8*)(pQ[0] + (16 * j + l15) * 32 + quad * 8);
            short8 b1 = *(const short8*)(pQ[1] + (16 * j + l15) * 32 + quad * 8);
            s1[j] = __builtin_amdgcn_mfma_f32_16x16x32_bf16(a0, b0, s1[j], 0, 0, 0);
            s1[j] = __builtin_amdgcn_mfma_f32_16x16x32_bf16(a1, b1, s1[j], 0, 0, 0);
        }
        #pragma unroll
        for (int j = 0; j < 2; ++j) {
            short8 b0 = *(const short8*)(pQs[0] + (16 * j + l15) * 32 + quad * 8);
            short8 b1 = *(const short8*)(pQs[1] + (16 * j + l15) * 32 + quad * 8);
            s2[j] = __builtin_amdgcn_mfma_f32_16x16x32_bf16(a0, b0, s2[j], 0, 0, 0);
            s2[j] = __builtin_amdgcn_mfma_f32_16x16x32_bf16(a1, b1, s2[j], 0, 0, 0);
        }
    }

    #pragma unroll
    for (int j = 0; j < 4; ++j)
        #pragma unroll
        for (int r = 0; r < 4; ++r) {
            const int rr = srow_base + r;
            const int cc = 16 * j + l15;
            smA[rr * 104 + cc] = f2b((cc <= rr) ? s1[j][r] : 0.0f);
        }
    #pragma unroll
    for (int j = 0; j < 2; ++j)
        #pragma unroll
        for (int r = 0; r < 4; ++r) {
            const int m  = 16 * j + l15;
            const int rr = srow_base + r;
            smA[rr * 104 + 64 + m] = f2b((m <= blk) ? s2[j][r] : 0.0f);
        }
    __syncthreads();

    // ---- Phase B: out = [S1|S2] @ smVT^T  (K=96, N=128) ----
    f32x4 o[8] = {};
    const u16* arow = smA + (16 * wid + l15) * 104;
    #pragma unroll
    for (int ks = 0; ks < 3; ++ks) {
        short8 as = *(const short8*)(arow + 32 * ks + quad * 8);
        #pragma unroll
        for (int nt = 0; nt < 8; ++nt) {
            short8 bs = *(const short8*)(smVT + (16 * nt + l15) * 104 + 32 * ks + quad * 8);
            o[nt] = __builtin_amdgcn_mfma_f32_16x16x32_bf16(as, bs, o[nt], 0, 0, 0);
        }
    }
    #pragma unroll
    for (int nt = 0; nt < 8; ++nt) {
        const int col = e0 + 16 * nt + l15;
        const float bvv = bu[col];
        #pragma unroll
        for (int r = 0; r < 4; ++r)
            out[(row0 + srow_base + r) * (size_t)EMB_D + col] = o[nt][r] + bvv;
    }
}

extern "C" void kernel_launch(void* const* d_in, const int* in_sizes, int n_in,
                              void* d_out, int out_size, void* d_ws, size_t ws_size,
                              hipStream_t stream)
{
    const float* x  = (const float*)d_in[0];
    const float* Wk = (const float*)d_in[1];
    const float* bk = (const float*)d_in[2];
    const float* Wq = (const float*)d_in[3];
    const float* bq = (const float*)d_in[4];
    const float* Wv = (const float*)d_in[5];
    const float* bv = (const float*)d_in[6];
    const float* Wu = (const float*)d_in[7];
    const float* bu = (const float*)d_in[8];
    float* out = (float*)d_out;

    char* w = (char*)d_ws;
    u16*   KQV     = (u16*)  (w + ((size_t)0  << 20));
    u16*   xb      = (u16*)  (w + ((size_t)32 << 20));
    u16*   wcat    = (u16*)  (w + ((size_t)40 << 20));
    float* biascat = (float*)(w + ((size_t)44 << 20));

    hipLaunchKernelGGL(prep_k, dim3(4657), dim3(256), 0, stream,
                       x, Wk, Wq, Wv, Wu, bk, bq, bv, xb, wcat, biascat);
    hipLaunchKernelGGL(kqv_gemm_k, dim3(256), dim3(512), 0, stream, xb, wcat, biascat, KQV);
    hipLaunchKernelGGL(heads_k, dim3(NBLK, BB, 4), dim3(256), 0, stream, KQV, bu, out);
}

// Round 3
// 141.538 us; speedup vs baseline: 1.0529x; 1.0005x over previous
//
#include <hip/hip_runtime.h>

// BlocksparseFixedSelfAttention: B=4, T=2048, EMB=512, KBLK=64.
// R9: heads_k restructured: z=2 (256 cols/block), 512 threads / 8 waves,
// grid (32,4,2)=256 blocks. Phase-A redundancy halved (was 4x over z);
// panel staging = one global_load_lds per panel per K-step. Bitwise-identical
// math. prep/kqv unchanged from R8.
// ws (MB): KQV bf16 32 @0 | xb 8 @32 | wcat bf16 2048x512 @40 | biascat @44

typedef unsigned short u16;
typedef __attribute__((ext_vector_type(8))) short short8;
typedef __attribute__((ext_vector_type(4))) float f32x4;

constexpr int TDIM  = 2048;
constexpr int EMB_D = 512;
constexpr int BB    = 4;
constexpr int NBLK  = 32;    // T / 64
constexpr int LDK   = 2048;  // KQV row stride (u16)

__device__ __forceinline__ u16 f2b(float f) {
    unsigned u = __float_as_uint(f);
    unsigned r = (u + 0x7FFFu + ((u >> 16) & 1u)) >> 16;
    return (u16)r;
}

// ---------------------------------------------------------------------------
// prep (one launch, all parts independent):
//  [0,32)      Wc MFMA blocks: wcat rows 1024+m = Wu2 @ Wv  (fp32 sources,
//              f2b in-register -> bitwise-identical to the old wub/wvtb path)
//  [32,4128)   cast x -> xb
//  [4128,4384) cast Wk -> wcat[0:512]
//  [4384,4640) cast Wq -> wcat[512:1024]
//  [4640,4656) biascat[1024+o] = Wu[o&511][.] . bv  (4 lanes/output + shfl)
//  4656        biascat[0:1024] = [bk|bq]
// ---------------------------------------------------------------------------
__global__ __launch_bounds__(256) void prep_k(
    const float* __restrict__ x, const float* __restrict__ Wk, const float* __restrict__ Wq,
    const float* __restrict__ Wv, const float* __restrict__ Wu,
    const float* __restrict__ bk, const float* __restrict__ bq, const float* __restrict__ bv,
    u16* __restrict__ xb, u16* __restrict__ wcat, float* __restrict__ biascat)
{
    const int bid = blockIdx.x, tid = threadIdx.x;
    if (bid < 32) {
        const int bm = (bid >> 2) * 128;   // M = 1024
        const int bn = (bid & 3) * 128;    // N = 512 (the k-dim of Wc)
        const int wid  = tid >> 6;
        const int lane = tid & 63;
        const int l15  = lane & 15;
        const int quad = lane >> 4;
        const int wm = (wid & 1) * 64;
        const int wn = (wid >> 1) * 64;

        f32x4 acc[4][4] = {};

        const float* Arow[4];
        #pragma unroll
        for (int i = 0; i < 4; ++i) {
            const int m = bm + wm + 16 * i + l15;
            Arow[i] = Wu + (size_t)(m & 511) * 1024 + (m >> 9) * 512 + quad * 8;
        }
        const float* Bcol[4];
        #pragma unroll
        for (int g = 0; g < 4; ++g)
            Bcol[g] = Wv + (bn + wn + 16 * g + l15) + (size_t)(quad * 8) * 512;

        for (int j0 = 0; j0 < 512; j0 += 32) {
            short8 a[4], b[4];
            #pragma unroll
            for (int i = 0; i < 4; ++i) {
                float4 v0 = *(const float4*)(Arow[i] + j0);
                float4 v1 = *(const float4*)(Arow[i] + j0 + 4);
                a[i] = (short8){(short)f2b(v0.x), (short)f2b(v0.y), (short)f2b(v0.z), (short)f2b(v0.w),
                                (short)f2b(v1.x), (short)f2b(v1.y), (short)f2b(v1.z), (short)f2b(v1.w)};
            }
            #pragma unroll
            for (int g = 0; g < 4; ++g) {
                const float* p = Bcol[g] + (size_t)j0 * 512;
                float v0 = p[0];          float v1 = p[512];
                float v2 = p[1024];       float v3 = p[1536];
                float v4 = p[2048];       float v5 = p[2560];
                float v6 = p[3072];       float v7 = p[3584];
                b[g] = (short8){(short)f2b(v0), (short)f2b(v1), (short)f2b(v2), (short)f2b(v3),
                                (short)f2b(v4), (short)f2b(v5), (short)f2b(v6), (short)f2b(v7)};
            }
            #pragma unroll
            for (int i = 0; i < 4; ++i)
                #pragma unroll
                for (int g = 0; g < 4; ++g)
                    acc[i][g] = __builtin_amdgcn_mfma_f32_16x16x32_bf16(a[i], b[g], acc[i][g], 0, 0, 0);
        }

        #pragma unroll
        for (int i = 0; i < 4; ++i)
            #pragma unroll
            for (int g = 0; g < 4; ++g) {
                const int col = bn + wn + 16 * g + l15;
                #pragma unroll
                for (int r = 0; r < 4; ++r) {
                    const int row = bm + wm + 16 * i + quad * 4 + r;
                    wcat[(size_t)(1024 + row) * 512 + col] = f2b(acc[i][g][r]);
                }
            }
    } else if (bid < 4640) {
        const float* src; u16* dst; int base;
        if (bid < 4128)      { src = x;  dst = xb;            base = (bid - 32) * 1024; }
        else if (bid < 4384) { src = Wk; dst = wcat;          base = (bid - 4128) * 1024; }
        else                 { src = Wq; dst = wcat + 262144; base = (bid - 4384) * 1024; }
        const int idx = base + tid * 4;
        float4 v = *(const float4*)(src + idx);
        ushort4 o = { f2b(v.x), f2b(v.y), f2b(v.z), f2b(v.w) };
        *(ushort4*)(dst + idx) = o;
    } else if (bid < 4656) {
        const int o = (bid - 4640) * 64 + (tid >> 2);
        const int p = tid & 3;
        const int n = o & 511, half = o >> 9;
        const float* wr = Wu + (size_t)n * 1024 + half * 512 + p * 128;
        const float* br = bv + p * 128;
        float s = 0.f;
        #pragma unroll
        for (int j = 0; j < 128; j += 4) {
            float4 a = *(const float4*)(wr + j);
            float4 b = *(const float4*)(br + j);
            s += a.x*b.x + a.y*b.y + a.z*b.z + a.w*b.w;
        }
        s += __shfl_xor(s, 1);
        s += __shfl_xor(s, 2);
        if (p == 0) biascat[1024 + o] = s;
    } else {
        const int idx = tid * 4;
        float4 v = (idx < 512) ? *(const float4*)(bk + idx)
                               : *(const float4*)(bq + idx - 512);
        *(float4*)(biascat + idx) = v;
    }
}

// ---------------------------------------------------------------------------
// KQV GEMM: C[m][n] = sum_k xb[m][k]*wcat[n][k] + biascat[n], bf16 out.
// 256x256 tile, BK=64, 512 threads (8 waves, 2Mx4N), 128 KiB LDS double-buffer,
// 8-phase schedule with counted vmcnt(4), swizzled LDS reads (inverse swizzle
// on the global source since global_load_lds writes linearly), setprio around
// MFMA clusters, bijective XCD block swizzle. M=8192, N=2048, K=512
// (8 K-tiles = 3 steady iterations + 1 peeled). Epilogue: LDS repack ->
// coalesced dwordx4 stores.
// ---------------------------------------------------------------------------
template<int MH, int KK>
__device__ __forceinline__ void mm16(const short8 (&a)[4], const short8 (&b)[2][4],
                                     f32x4 (&acc)[8][4])
{
    #pragma unroll
    for (int f = 0; f < 4; ++f)
        #pragma unroll
        for (int g = 0; g < 4; ++g)
            acc[MH * 4 + f][g] = __builtin_amdgcn_mfma_f32_16x16x32_bf16(
                a[f], b[KK][g], acc[MH * 4 + f][g], 0, 0, 0);
}

template<int SLOT, int MH>
__device__ __forceinline__ void lda4(short8 (&a)[4], const u16* sm, int arow, int koff)
{
    #pragma unroll
    for (int f = 0; f < 4; ++f)
        a[f] = *(const short8*)(sm + SLOT * 32768 + (arow + MH * 64 + f * 16) * 64 + koff);
}

template<int SLOT>
__device__ __forceinline__ void ldb4(short8 (&bk)[4], const u16* sm, int brow, int koff)
{
    #pragma unroll
    for (int g = 0; g < 4; ++g)
        bk[g] = *(const short8*)(sm + SLOT * 32768 + 16384 + (brow + g * 16) * 64 + koff);
}

#define STA(S, CI, T) __builtin_amdgcn_global_load_lds( \
    (const __attribute__((address_space(1))) void*)(Ag + (size_t)(CI) * 32768 + (T) * 64), \
    (__attribute__((address_space(3))) void*)(sm + (S) * 32768 + (CI) * 4096 + wid * 512), 16, 0, 0)
#define STB(S, CI, T) __builtin_amdgcn_global_load_lds( \
    (const __attribute__((address_space(1))) void*)(Bg + (size_t)(CI) * 32768 + (T) * 64), \
    (__attribute__((address_space(3))) void*)(sm + (S) * 32768 + 16384 + (CI) * 4096 + wid * 512), 16, 0, 0)
#define KBAR()  __builtin_amdgcn_s_barrier()
#define KPRIO(P) __builtin_amdgcn_s_setprio(P)
#define LGKM0() do { asm volatile("s_waitcnt lgkmcnt(0)" ::: "memory"); \
                     __builtin_amdgcn_sched_barrier(0); } while (0)
#define VMC4()  asm volatile("s_waitcnt vmcnt(4)" ::: "memory")
#define VMC0()  asm volatile("s_waitcnt vmcnt(0)" ::: "memory")

__global__ __launch_bounds__(512, 2) void kqv_gemm_k(
    const u16* __restrict__ A, const u16* __restrict__ W,
    const float* __restrict__ bias, u16* __restrict__ C)
{
    __shared__ u16 sm[65536];   // 128 KiB: [slot][A 16384 | B 16384] u16

    const int bid = blockIdx.x;
    const int wg  = (bid & 7) * 32 + (bid >> 3);   // bijective XCD swizzle (256 = 8*32)
    const int bm  = (wg & 31) * 256;               // 32 M-tiles
    const int bn  = (wg >> 5) * 256;               // 8 N-tiles (one per XCD)
    const int tid  = threadIdx.x;
    const int wid  = tid >> 6;
    const int lane = tid & 63;
    const int l15  = lane & 15;
    const int quad = lane >> 4;
    const int wm = wid >> 2;    // 0..1
    const int wn = wid & 3;     // 0..3

    const int stgrow = wid * 8 + (lane >> 3);                  // row within chunk
    const int stgk   = ((lane & 7) ^ ((lane >> 3) & 7)) << 3;  // swizzled 16B chunk
    const u16* Ag = A + (size_t)(bm + stgrow) * 512 + stgk;
    const u16* Bg = W + (size_t)(bn + stgrow) * 512 + stgk;

    const int r7     = l15 & 7;
    const int arow   = wm * 128 + l15;
    const int brow   = wn * 64 + l15;
    const int off_k0 = ((quad ^ r7) << 3);          // kf=0 swizzled 16B chunk
    const int off_k1 = (((4 | quad) ^ r7) << 3);    // kf=1

    f32x4 acc[8][4] = {};
    short8 a[4], b[2][4];

    // prologue: tile0 full (oldest 8 loads) + tile1 {a0,a2,b0,b1}
    STA(0,0,0); STA(0,2,0); STB(0,0,0); STB(0,1,0);
    STB(0,2,0); STB(0,3,0); STA(0,1,0); STA(0,3,0);
    STA(1,0,1); STA(1,2,1); STB(1,0,1); STB(1,1,1);
    VMC4(); KBAR();

    for (int it = 0; it < 3; ++it) {
        const int t = 2 * it;
        ldb4<0>(b[0], sm, brow, off_k0); lda4<0,0>(a, sm, arow, off_k0);
        STB(1,2,t+1); STB(1,3,t+1);
        KBAR(); LGKM0(); KPRIO(1); mm16<0,0>(a, b, acc); KPRIO(0); KBAR();
        ldb4<0>(b[1], sm, brow, off_k1); lda4<0,0>(a, sm, arow, off_k1);
        STA(1,1,t+1); STA(1,3,t+1);
        KBAR(); LGKM0(); KPRIO(1); mm16<0,1>(a, b, acc); KPRIO(0); KBAR();
        lda4<0,1>(a, sm, arow, off_k0);
        STA(0,0,t+2); STA(0,2,t+2);
        KBAR(); LGKM0(); KPRIO(1); mm16<1,0>(a, b, acc); KPRIO(0); KBAR();
        lda4<0,1>(a, sm, arow, off_k1);
        STB(0,0,t+2); STB(0,1,t+2);
        KBAR(); LGKM0(); KPRIO(1); mm16<1,1>(a, b, acc); KPRIO(0); VMC4(); KBAR();
        ldb4<1>(b[0], sm, brow, off_k0); lda4<1,0>(a, sm, arow, off_k0);
        STB(0,2,t+2); STB(0,3,t+2);
        KBAR(); LGKM0(); KPRIO(1); mm16<0,0>(a, b, acc); KPRIO(0); KBAR();
        ldb4<1>(b[1], sm, brow, off_k1); lda4<1,0>(a, sm, arow, off_k1);
        STA(0,1,t+2); STA(0,3,t+2);
        KBAR(); LGKM0(); KPRIO(1); mm16<0,1>(a, b, acc); KPRIO(0); KBAR();
        lda4<1,1>(a, sm, arow, off_k0);
        STA(1,0,t+3); STA(1,2,t+3);
        KBAR(); LGKM0(); KPRIO(1); mm16<1,0>(a, b, acc); KPRIO(0); KBAR();
        lda4<1,1>(a, sm, arow, off_k1);
        STB(1,0,t+3); STB(1,1,t+3);
        KBAR(); LGKM0(); KPRIO(1); mm16<1,1>(a, b, acc); KPRIO(0); VMC4(); KBAR();
    }

    ldb4<0>(b[0], sm, brow, off_k0); lda4<0,0>(a, sm, arow, off_k0);
    STB(1,2,7); STB(1,3,7);
    KBAR(); LGKM0(); KPRIO(1); mm16<0,0>(a, b, acc); KPRIO(0); KBAR();
    ldb4<0>(b[1], sm, brow, off_k1); lda4<0,0>(a, sm, arow, off_k1);
    STA(1,1,7); STA(1,3,7);
    KBAR(); LGKM0(); KPRIO(1); mm16<0,1>(a, b, acc); KPRIO(0); KBAR();
    lda4<0,1>(a, sm, arow, off_k0);
    KBAR(); LGKM0(); KPRIO(1); mm16<1,0>(a, b, acc); KPRIO(0); KBAR();
    lda4<0,1>(a, sm, arow, off_k1);
    KBAR(); LGKM0(); KPRIO(1); mm16<1,1>(a, b, acc); KPRIO(0); VMC0(); KBAR();
    ldb4<1>(b[0], sm, brow, off_k0); lda4<1,0>(a, sm, arow, off_k0);
    KBAR(); LGKM0(); KPRIO(1); mm16<0,0>(a, b, acc); KPRIO(0); KBAR();
    ldb4<1>(b[1], sm, brow, off_k1); lda4<1,0>(a, sm, arow, off_k1);
    KBAR(); LGKM0(); KPRIO(1); mm16<0,1>(a, b, acc); KPRIO(0); KBAR();
    lda4<1,1>(a, sm, arow, off_k0);
    KBAR(); LGKM0(); KPRIO(1); mm16<1,0>(a, b, acc); KPRIO(0); KBAR();
    lda4<1,1>(a, sm, arow, off_k1);
    KBAR(); LGKM0(); KPRIO(1); mm16<1,1>(a, b, acc); KPRIO(0);

    // epilogue: bias + bf16 round -> LDS [256][256] u16 -> coalesced stores
    __syncthreads();
    #pragma unroll
    for (int mf = 0; mf < 8; ++mf) {
        #pragma unroll
        for (int g = 0; g < 4; ++g) {
            const int col = wn * 64 + g * 16 + l15;
            const float bvv = bias[bn + col];
            #pragma unroll
            for (int r = 0; r < 4; ++r) {
                const int row = wm * 128 + mf * 16 + quad * 4 + r;
                sm[row * 256 + col] = f2b(acc[mf][g][r] + bvv);
            }
        }
    }
    __syncthreads();
    {
        const int rr = tid >> 5;          // 0..15
        const int ck = tid & 31;          // 0..31 (16B col chunks)
        #pragma unroll
        for (int p = 0; p < 16; ++p) {
            const int row = p * 16 + rr;
            short8 v = *(const short8*)(sm + row * 256 + ck * 8);
            *(short8*)(C + (size_t)(bm + row) * LDK + bn + ck * 8) = v;
        }
    }
}

#undef STA
#undef STB
#undef KBAR
#undef KPRIO
#undef LGKM0
#undef VMC4
#undef VMC0

// ---------------------------------------------------------------------------
// heads (R9): grid (32 blk, 4 b, 2 e-chunk), 512 threads / 8 waves.
//  Wave (rw,ch) = (wid&3, wid>>2).
//  Phase A (BK=64, one global_load_lds per panel per K-step):
//   S1 = K_blk.Q_blk^T (64x64): wave owns row-tile rw, col-tiles {2ch,2ch+1}.
//   S2 = K_blk.Qsel^T (64x32): wave owns col-tile ch.
//   masks c<=r / m<=blk; S -> smA bf16. (identical accumulation order to R8)
//  Phase B: out[:, e0:+256] = [S1|S2] @ smVT^T (K=96, N=256; wave: rows 16rw,
//   nt-tiles 8ch+0..7).
// ---------------------------------------------------------------------------
__global__ __launch_bounds__(512) void heads_k(
    const u16* __restrict__ KQV, const float* __restrict__ bu, float* __restrict__ out)
{
    __shared__ u16 smA[64 * 104];     // [row][0:64 S1 | 64:96 S2]
    __shared__ u16 smVT[256 * 104];   // [e][0:64 VU1^T | 64:96 VU2sel^T]
    __shared__ u16 pK[2][64 * 32];    // k-panels (BK=64 = 2 x 32)
    __shared__ u16 pQ[2][64 * 32];
    __shared__ u16 pQs[2][32 * 32];

    const int blk = blockIdx.x, b = blockIdx.y;
    const int e0 = blockIdx.z * 256;
    const int tid = threadIdx.x;
    const int wid = tid >> 6, lane = tid & 63;
    const int l15 = lane & 15, quad = lane >> 4;
    const int rw = wid & 3, ch = wid >> 2;
    const size_t row0 = (size_t)b * TDIM + (size_t)blk * 64;
    const size_t brow = (size_t)b * TDIM;
    const int srow_base = 16 * rw + quad * 4;

    // ---- VU^T staging (independent of S; overlaps Phase A latency) ----
    #pragma unroll
    for (int it = 0; it < 4; ++it) {
        const int id = tid + 512 * it;         // 0..2047
        const int c  = id & 63;
        const int eo = (id >> 6) * 8;          // 0..248
        short8 v = *(const short8*)(KQV + (row0 + c) * (size_t)LDK + 1024 + e0 + eo);
        #pragma unroll
        for (int i = 0; i < 8; ++i) smVT[(eo + i) * 104 + c] = (u16)v[i];
    }
    #pragma unroll
    for (int it = 0; it < 2; ++it) {
        const int id = tid + 512 * it;         // 0..1023
        const int m  = id & 31;
        const int eo = (id >> 5) * 8;          // 0..248
        short8 v = *(const short8*)(KQV + (brow + 64 * m) * (size_t)LDK + 1536 + e0 + eo);
        #pragma unroll
        for (int i = 0; i < 8; ++i) smVT[(eo + i) * 104 + 64 + m] = (u16)v[i];
    }

    // ---- Phase A ----
    f32x4 s1[2] = {}; f32x4 s2 = {};
    // staging map: elem e = tid*8 of pK/pQ ([half][row][32]):
    //   half = tid>>8, row = (tid>>2)&63, k8 = (tid&3)*8
    const int strow  = (tid >> 2) & 63;
    const int sthalf = tid >> 8;
    const int stk    = (tid & 3) * 8;
    const u16* Kg = KQV + (row0 + strow) * (size_t)LDK + sthalf * 32 + stk;
    const u16* Qg = Kg + 512;
    // pQs ([half][row][32], rows 0..31): half = (tid>>7)&1, row = (tid>>2)&31
    const int qrow  = (tid >> 2) & 31;
    const int qhalf = (tid >> 7) & 1;
    const u16* Qsg = KQV + (brow + (size_t)64 * qrow) * (size_t)LDK + 512 + qhalf * 32 + stk;
    char* dK  = (char*)pK  + wid * 1024;
    char* dQ  = (char*)pQ  + wid * 1024;
    char* dQs = (char*)pQs + wid * 1024;   // only wid<4

    for (int k0 = 0; k0 < 512; k0 += 64) {
        __syncthreads();
        __builtin_amdgcn_global_load_lds(
            (const __attribute__((address_space(1))) void*)(Kg + k0),
            (__attribute__((address_space(3))) void*)dK, 16, 0, 0);
        __builtin_amdgcn_global_load_lds(
            (const __attribute__((address_space(1))) void*)(Qg + k0),
            (__attribute__((address_space(3))) void*)dQ, 16, 0, 0);
        if (wid < 4)
            __builtin_amdgcn_global_load_lds(
                (const __attribute__((address_space(1))) void*)(Qsg + k0),
                (__attribute__((address_space(3))) void*)dQs, 16, 0, 0);
        __syncthreads();

        short8 a0 = *(const short8*)(pK[0] + (16 * rw + l15) * 32 + quad * 8);
        short8 a1 = *(const short8*)(pK[1] + (16 * rw + l15) * 32 + quad * 8);
        #pragma unroll
        for (int jj = 0; jj < 2; ++jj) {
            const int j = 2 * ch + jj;
            short8 b0 = *(const short8*)(pQ[0] + (16 * j + l15) * 32 + quad * 8);
            short8 b1 = *(const short8*)(pQ[1] + (16 * j + l15) * 32 + quad * 8);
            s1[jj] = __builtin_amdgcn_mfma_f32_16x16x32_bf16(a0, b0, s1[jj], 0, 0, 0);
            s1[jj] = __builtin_amdgcn_mfma_f32_16x16x32_bf16(a1, b1, s1[jj], 0, 0, 0);
        }
        {
            short8 b0 = *(const short8*)(pQs[0] + (16 * ch + l15) * 32 + quad * 8);
            short8 b1 = *(const short8*)(pQs[1] + (16 * ch + l15) * 32 + quad * 8);
            s2 = __builtin_amdgcn_mfma_f32_16x16x32_bf16(a0, b0, s2, 0, 0, 0);
            s2 = __builtin_amdgcn_mfma_f32_16x16x32_bf16(a1, b1, s2, 0, 0, 0);
        }
    }

    #pragma unroll
    for (int jj = 0; jj < 2; ++jj)
        #pragma unroll
        for (int r = 0; r < 4; ++r) {
            const int rr = srow_base + r;
            const int cc = 32 * ch + 16 * jj + l15;
            smA[rr * 104 + cc] = f2b((cc <= rr) ? s1[jj][r] : 0.0f);
        }
    #pragma unroll
    for (int r = 0; r < 4; ++r) {
        const int m  = 16 * ch + l15;
        const int rr = srow_base + r;
        smA[rr * 104 + 64 + m] = f2b((m <= blk) ? s2[r] : 0.0f);
    }
    __syncthreads();

    // ---- Phase B: out = [S1|S2] @ smVT^T  (K=96, N=256) ----
    f32x4 o[8] = {};
    const u16* arow = smA + (16 * rw + l15) * 104;
    #pragma unroll
    for (int ks = 0; ks < 3; ++ks) {
        short8 as = *(const short8*)(arow + 32 * ks + quad * 8);
        #pragma unroll
        for (int nt = 0; nt < 8; ++nt) {
            short8 bs = *(const short8*)(smVT + (16 * (8 * ch + nt) + l15) * 104 + 32 * ks + quad * 8);
            o[nt] = __builtin_amdgcn_mfma_f32_16x16x32_bf16(as, bs, o[nt], 0, 0, 0);
        }
    }
    #pragma unroll
    for (int nt = 0; nt < 8; ++nt) {
        const int col = e0 + 16 * (8 * ch + nt) + l15;
        const float bvv = bu[col];
        #pragma unroll
        for (int r = 0; r < 4; ++r)
            out[(row0 + srow_base + r) * (size_t)EMB_D + col] = o[nt][r] + bvv;
    }
}

extern "C" void kernel_launch(void* const* d_in, const int* in_sizes, int n_in,
                              void* d_out, int out_size, void* d_ws, size_t ws_size,
                              hipStream_t stream)
{
    const float* x  = (const float*)d_in[0];
    const float* Wk = (const float*)d_in[1];
    const float* bk = (const float*)d_in[2];
    const float* Wq = (const float*)d_in[3];
    const float* bq = (const float*)d_in[4];
    const float* Wv = (const float*)d_in[5];
    const float* bv = (const float*)d_in[6];
    const float* Wu = (const float*)d_in[7];
    const float* bu = (const float*)d_in[8];
    float* out = (float*)d_out;

    char* w = (char*)d_ws;
    u16*   KQV     = (u16*)  (w + ((size_t)0  << 20));
    u16*   xb      = (u16*)  (w + ((size_t)32 << 20));
    u16*   wcat    = (u16*)  (w + ((size_t)40 << 20));
    float* biascat = (float*)(w + ((size_t)44 << 20));

    hipLaunchKernelGGL(prep_k, dim3(4657), dim3(256), 0, stream,
                       x, Wk, Wq, Wv, Wu, bk, bq, bv, xb, wcat, biascat);
    hipLaunchKernelGGL(kqv_gemm_k, dim3(256), dim3(512), 0, stream, xb, wcat, biascat, KQV);
    hipLaunchKernelGGL(heads_k, dim3(NBLK, BB, 2), dim3(512), 0, stream, KQV, bu, out);
}